// Round 16
// baseline (818.998 us; speedup 1.0000x reference)
//
#include <hip/hip_runtime.h>

#define DIMC 512
#define HEADS 8
#define HD 64
#define WINS 10
#define SHIFT_SZ 5
#define FRAMES 1000
#define NWIN 100
#define BATCH 64
#define TOKENS 64000
#define HIDDEN 2048

typedef unsigned short u16;
typedef __attribute__((ext_vector_type(8))) short bf16x8;
typedef __attribute__((ext_vector_type(4))) float f32x4;

__device__ __forceinline__ float bf2f(u16 u) { return __uint_as_float(((unsigned)u) << 16); }
__device__ __forceinline__ u16 f2bf(float f) {
    unsigned u = __float_as_uint(f);
    u += 0x7fffu + ((u >> 16) & 1u);
    return (u16)(u >> 16);
}

// ---------------- fp32 -> bf16 weight conversion ----------------
__global__ __launch_bounds__(256) void cvt_kernel(const float* __restrict__ src,
                                                  u16* __restrict__ dst, int n) {
    const int i = (blockIdx.x * 256 + threadIdx.x) * 4;
    if (i < n) {
        const float4 v = *(const float4*)(src + i);
        *(ushort4*)(dst + i) = make_ushort4(f2bf(v.x), f2bf(v.y), f2bf(v.z), f2bf(v.w));
    }
}

// ---------------- LayerNorm fp32-in: bf16 LN out (rolled -SH) + raw bf16 copy ----------------
template <int SH>
__global__ __launch_bounds__(256) void ln_kernel(const float* __restrict__ x,
                                                 const float* __restrict__ w,
                                                 const float* __restrict__ b,
                                                 u16* __restrict__ out,
                                                 u16* __restrict__ xb) {
    const int wave = threadIdx.x >> 6, lane = threadIdx.x & 63;
    const int row = blockIdx.x * 4 + wave;
    const float4* rp = (const float4*)(x + (size_t)row * DIMC);
    const float4 v0 = rp[lane];
    const float4 v1 = rp[64 + lane];
    float f[8] = {v0.x, v0.y, v0.z, v0.w, v1.x, v1.y, v1.z, v1.w};
    float sum = 0.f, sq = 0.f;
#pragma unroll
    for (int i = 0; i < 8; i++) { sum += f[i]; sq += f[i] * f[i]; }
#pragma unroll
    for (int off = 32; off >= 1; off >>= 1) {
        sum += __shfl_xor(sum, off);
        sq += __shfl_xor(sq, off);
    }
    const float mean = sum * (1.f / DIMC);
    const float var = sq * (1.f / DIMC) - mean * mean;
    const float rstd = rsqrtf(var + 1e-5f);

    if (xb) {
        u16* xp = xb + (size_t)row * DIMC;
        *(ushort4*)(xp + 4 * lane) = make_ushort4(f2bf(f[0]), f2bf(f[1]), f2bf(f[2]), f2bf(f[3]));
        *(ushort4*)(xp + 256 + 4 * lane) = make_ushort4(f2bf(f[4]), f2bf(f[5]), f2bf(f[6]), f2bf(f[7]));
    }

    const float4 w0 = ((const float4*)w)[lane], w1 = ((const float4*)w)[64 + lane];
    const float4 b0 = ((const float4*)b)[lane], b1 = ((const float4*)b)[64 + lane];
    const float wf[8] = {w0.x, w0.y, w0.z, w0.w, w1.x, w1.y, w1.z, w1.w};
    const float bf[8] = {b0.x, b0.y, b0.z, b0.w, b1.x, b1.y, b1.z, b1.w};
    u16 o[8];
#pragma unroll
    for (int i = 0; i < 8; i++) o[i] = f2bf((f[i] - mean) * rstd * wf[i] + bf[i]);

    int dst = row;
    if (SH) {
        int bb = row / FRAMES;
        int t = row - bb * FRAMES;
        int td = t - SH; if (td < 0) td += FRAMES;
        dst = bb * FRAMES + td;
    }
    u16* op = out + (size_t)dst * DIMC;
    *(ushort4*)(op + 4 * lane) = make_ushort4(o[0], o[1], o[2], o[3]);
    *(ushort4*)(op + 256 + 4 * lane) = make_ushort4(o[4], o[5], o[6], o[7]);
}

// ---------------- LayerNorm bf16-in (for LN2 over x2b) ----------------
__global__ __launch_bounds__(256) void ln_kernel_bf(const u16* __restrict__ x,
                                                    const float* __restrict__ w,
                                                    const float* __restrict__ b,
                                                    u16* __restrict__ out) {
    const int wave = threadIdx.x >> 6, lane = threadIdx.x & 63;
    const int row = blockIdx.x * 4 + wave;
    const uint4 v = ((const uint4*)(x + (size_t)row * DIMC))[lane];
    const unsigned uv[4] = {v.x, v.y, v.z, v.w};
    float f[8];
    float sum = 0.f, sq = 0.f;
#pragma unroll
    for (int i = 0; i < 4; i++) {
        float a = __uint_as_float(uv[i] << 16);
        float c = __uint_as_float(uv[i] & 0xffff0000u);
        f[2 * i] = a; f[2 * i + 1] = c;
        sum += a + c; sq += a * a + c * c;
    }
#pragma unroll
    for (int off = 32; off >= 1; off >>= 1) {
        sum += __shfl_xor(sum, off);
        sq += __shfl_xor(sq, off);
    }
    const float mean = sum * (1.f / DIMC);
    const float var = sq * (1.f / DIMC) - mean * mean;
    const float rstd = rsqrtf(var + 1e-5f);

    const float4 w0 = ((const float4*)w)[2 * lane], w1 = ((const float4*)w)[2 * lane + 1];
    const float4 b0 = ((const float4*)b)[2 * lane], b1 = ((const float4*)b)[2 * lane + 1];
    const float wf[8] = {w0.x, w0.y, w0.z, w0.w, w1.x, w1.y, w1.z, w1.w};
    const float bf[8] = {b0.x, b0.y, b0.z, b0.w, b1.x, b1.y, b1.z, b1.w};
    u16 o[8];
#pragma unroll
    for (int i = 0; i < 8; i++) o[i] = f2bf((f[i] - mean) * rstd * wf[i] + bf[i]);
    uint4 ov;
    ov.x = (unsigned)o[0] | ((unsigned)o[1] << 16);
    ov.y = (unsigned)o[2] | ((unsigned)o[3] << 16);
    ov.z = (unsigned)o[4] | ((unsigned)o[5] << 16);
    ov.w = (unsigned)o[6] | ((unsigned)o[7] << 16);
    ((uint4*)(out + (size_t)row * DIMC))[lane] = ov;
}

#define GLD16(gp, lp)                                                                     \
    __builtin_amdgcn_global_load_lds((const __attribute__((address_space(1))) void*)(gp), \
                                     (__attribute__((address_space(3))) void*)(lp), 16, 0, 0)

// ---------------- gemm_bt (BN=128): R13-verified; proj (MODE 1) & fc2 (MODE 3) ----
template <int MODE>
__global__ __launch_bounds__(256, 2) void gemm_bt(const u16* __restrict__ A,
                                                  const u16* __restrict__ W,
                                                  const float* __restrict__ bias,
                                                  u16* __restrict__ Cb,
                                                  float* __restrict__ Cf,
                                                  const u16* __restrict__ Rb,
                                                  int Nn, int K, int nbn) {
    __shared__ __align__(16) u16 smem[36864];
    const int tid = threadIdx.x;
    const int w = tid >> 6, l = tid & 63;

    const int nwg = gridDim.x;
    const int q8 = nwg >> 3, r8 = nwg & 7;
    const int xcd = blockIdx.x & 7, bidx = blockIdx.x >> 3;
    const int swz = (xcd < r8 ? xcd * (q8 + 1) : r8 * (q8 + 1) + (xcd - r8) * q8) + bidx;
    const int bm = swz / nbn, bn = swz - bm * nbn;

    const int wr = w >> 1, wc = w & 1;
    const int lrow = l & 15, lq = l >> 4;

    f32x4 acc[8][4];
#pragma unroll
    for (int m = 0; m < 8; m++)
#pragma unroll
        for (int n = 0; n < 4; n++) acc[m][n] = (f32x4)0.0f;

    const int gsrc8 = (((tid & 3) ^ ((tid >> 3) & 3)) << 3);
    const u16* Ag = A + (size_t)(bm * 256 + (tid >> 2)) * K + gsrc8;
    const u16* Bg = W + (size_t)(bn * 128 + (tid >> 2)) * K + gsrc8;
    const size_t rowoff = (size_t)64 * K;
    const int lb = w * 512;

#define STAGE(buf, kt) do {                                       \
        u16* sb_ = smem + (buf) * 12288;                          \
        GLD16(Ag + (kt), sb_ + lb);                               \
        GLD16(Ag + rowoff + (kt), sb_ + 2048 + lb);               \
        GLD16(Ag + 2 * rowoff + (kt), sb_ + 4096 + lb);           \
        GLD16(Ag + 3 * rowoff + (kt), sb_ + 6144 + lb);           \
        GLD16(Bg + (kt), sb_ + 8192 + lb);                        \
        GLD16(Bg + rowoff + (kt), sb_ + 10240 + lb);              \
    } while (0)

    const int gran = ((lq ^ ((lrow >> 1) & 3)) << 3);
    const int arow = (wr * 128 + lrow) * 32 + gran;
    const int brow = 8192 + (wc * 64 + lrow) * 32 + gran;

#define COMPUTE(buf) do {                                                          \
        const u16* sb = smem + (buf) * 12288;                                      \
        bf16x8 bv[4];                                                              \
        _Pragma("unroll")                                                          \
        for (int n = 0; n < 4; n++) bv[n] = *(const bf16x8*)(sb + brow + n * 512); \
        _Pragma("unroll")                                                          \
        for (int m = 0; m < 8; m++) {                                              \
            const bf16x8 af = *(const bf16x8*)(sb + arow + m * 512);               \
            _Pragma("unroll")                                                      \
            for (int n = 0; n < 4; n++)                                            \
                acc[m][n] = __builtin_amdgcn_mfma_f32_16x16x32_bf16(bv[n], af, acc[m][n], 0, 0, 0); \
        }                                                                          \
    } while (0)

    const int nt = K >> 5;
    STAGE(0, 0);
    STAGE(1, 32);
    int cb = 0;
    for (int t = 0; t < nt - 1; ++t) {
        asm volatile("s_waitcnt vmcnt(6)" ::: "memory");
        __builtin_amdgcn_s_barrier();
        __builtin_amdgcn_sched_barrier(0);
        if (t + 2 < nt) {                      // stage first (T3 recipe; safe: barrier
            const int sbuf = cb == 0 ? 2 : cb - 1;  // certifies COMPUTE(t-1) done on (t+2)%3)
            STAGE(sbuf, (t + 2) * 32);
        }
        COMPUTE(cb);
        cb = cb == 2 ? 0 : cb + 1;
    }
    asm volatile("s_waitcnt vmcnt(0)" ::: "memory");
    __builtin_amdgcn_s_barrier();
    __builtin_amdgcn_sched_barrier(0);
    COMPUTE(cb);

    if (MODE == 1) {
        __syncthreads();
#pragma unroll
        for (int m = 0; m < 8; m++) {
            const int row = wr * 128 + m * 16 + lrow;
            const int sw = (row & 7) << 3;
#pragma unroll
            for (int n = 0; n < 4; n++) {
                const int col = wc * 64 + n * 16 + lq * 4;
                const float4 b4 = *(const float4*)(bias + bn * 128 + col);
                *(ushort4*)(smem + row * 128 + (col ^ sw)) =
                    make_ushort4(f2bf(acc[m][n][0] + b4.x), f2bf(acc[m][n][1] + b4.y),
                                 f2bf(acc[m][n][2] + b4.z), f2bf(acc[m][n][3] + b4.w));
            }
        }
        __syncthreads();
        const int c8 = lrow * 8;
#pragma unroll
        for (int i = 0; i < 16; i++) {
            const int r = w * 64 + i * 4 + lq;
            const uint4 val = *(const uint4*)(smem + r * 128 + (c8 ^ ((r & 7) << 3)));
            const int grow = bm * 256 + r;
            int bb = grow / FRAMES;
            int tr = grow - bb * FRAMES;
            int td = tr + SHIFT_SZ; if (td >= FRAMES) td -= FRAMES;
            const size_t dr = (size_t)(bb * FRAMES + td) * DIMC + bn * 128 + c8;
            const uint4 rv = *(const uint4*)(Rb + dr);
            const u16* vp = (const u16*)&val;
            const u16* rp2 = (const u16*)&rv;
            u16 o[8];
#pragma unroll
            for (int k = 0; k < 8; k++) o[k] = f2bf(bf2f(vp[k]) + bf2f(rp2[k]));
            uint4 ov;
            ov.x = (unsigned)o[0] | ((unsigned)o[1] << 16);
            ov.y = (unsigned)o[2] | ((unsigned)o[3] << 16);
            ov.z = (unsigned)o[4] | ((unsigned)o[5] << 16);
            ov.w = (unsigned)o[6] | ((unsigned)o[7] << 16);
            *(uint4*)(Cb + dr) = ov;
        }
    } else {
        // MODE 3: fp32 direct with bf16 residual
#pragma unroll
        for (int m = 0; m < 8; m++) {
            const int grow = bm * 256 + wr * 128 + m * 16 + lrow;
#pragma unroll
            for (int n = 0; n < 4; n++) {
                const int gcb = bn * 128 + wc * 64 + n * 16 + lq * 4;
                const float4 b4 = *(const float4*)(bias + gcb);
                const size_t dr = (size_t)grow * Nn + gcb;
                const ushort4 rb = *(const ushort4*)(Rb + dr);
                float4 o;
                o.x = acc[m][n][0] + b4.x + bf2f(rb.x);
                o.y = acc[m][n][1] + b4.y + bf2f(rb.y);
                o.z = acc[m][n][2] + b4.z + bf2f(rb.z);
                o.w = acc[m][n][3] + b4.w + bf2f(rb.w);
                *(float4*)(Cf + dr) = o;
            }
        }
    }
#undef COMPUTE
#undef STAGE
}

// ---------------- gemm_w (BN=256, 512 thr, 8 waves 2Mx4N): qkv (0) & fc1 (2) ----
// Same R13 sync skeleton; 4 loads/stage -> counted vmcnt(4); 96 KiB LDS;
// bounce epilogue in two 128-row passes (R14-verified 256-wide swizzle).
template <int MODE>
__global__ __launch_bounds__(512, 2) void gemm_w(const u16* __restrict__ A,
                                                 const u16* __restrict__ W,
                                                 const float* __restrict__ bias,
                                                 u16* __restrict__ Cb,
                                                 int Nn, int K, int nbn) {
    __shared__ __align__(16) u16 smem[49152];  // 3 x 32 KiB; bounce half = 64 KiB
    const int tid = threadIdx.x;
    const int w = tid >> 6, l = tid & 63;

    const int nwg = gridDim.x;
    const int q8 = nwg >> 3, r8 = nwg & 7;
    const int xcd = blockIdx.x & 7, bidx = blockIdx.x >> 3;
    const int swz = (xcd < r8 ? xcd * (q8 + 1) : r8 * (q8 + 1) + (xcd - r8) * q8) + bidx;
    const int bm = swz / nbn, bn = swz - bm * nbn;

    const int wm = w >> 2, wn = w & 3;
    const int lrow = l & 15, lq = l >> 4;

    f32x4 acc[8][4];
#pragma unroll
    for (int m = 0; m < 8; m++)
#pragma unroll
        for (int n = 0; n < 4; n++) acc[m][n] = (f32x4)0.0f;

    // stage: one issue = 512 thr x 16B = 128 rows x 32 u16
    const int gsrc8 = (((tid & 3) ^ ((tid >> 3) & 3)) << 3);
    const u16* Ag = A + (size_t)(bm * 256 + (tid >> 2)) * K + gsrc8;
    const u16* Wg = W + (size_t)(bn * 256 + (tid >> 2)) * K + gsrc8;
    const size_t roff = (size_t)128 * K;
    const int lb = w * 512;

#define STAGEW(buf, kt) do {                                      \
        u16* sb_ = smem + (buf) * 16384;                          \
        GLD16(Ag + (kt), sb_ + lb);                               \
        GLD16(Ag + roff + (kt), sb_ + 4096 + lb);                 \
        GLD16(Wg + (kt), sb_ + 8192 + lb);                        \
        GLD16(Wg + roff + (kt), sb_ + 12288 + lb);                \
    } while (0)

    const int gran = ((lq ^ ((lrow >> 1) & 3)) << 3);
    const int arow = (wm * 128 + lrow) * 32 + gran;          // + m*512
    const int brow = 8192 + (wn * 64 + lrow) * 32 + gran;    // + n*512

#define COMPUTEW(buf) do {                                                         \
        const u16* sb = smem + (buf) * 16384;                                      \
        bf16x8 bv[4];                                                              \
        _Pragma("unroll")                                                          \
        for (int n = 0; n < 4; n++) bv[n] = *(const bf16x8*)(sb + brow + n * 512); \
        _Pragma("unroll")                                                          \
        for (int m = 0; m < 8; m++) {                                              \
            const bf16x8 af = *(const bf16x8*)(sb + arow + m * 512);               \
            _Pragma("unroll")                                                      \
            for (int n = 0; n < 4; n++)                                            \
                acc[m][n] = __builtin_amdgcn_mfma_f32_16x16x32_bf16(bv[n], af, acc[m][n], 0, 0, 0); \
        }                                                                          \
    } while (0)

    const int nt = K >> 5;
    STAGEW(0, 0);
    STAGEW(1, 32);
    int cb = 0;
    for (int t = 0; t < nt - 1; ++t) {
        asm volatile("s_waitcnt vmcnt(4)" ::: "memory");
        __builtin_amdgcn_s_barrier();
        __builtin_amdgcn_sched_barrier(0);
        if (t + 2 < nt) {
            const int sbuf = cb == 0 ? 2 : cb - 1;
            STAGEW(sbuf, (t + 2) * 32);
        }
        COMPUTEW(cb);
        cb = cb == 2 ? 0 : cb + 1;
    }
    asm volatile("s_waitcnt vmcnt(0)" ::: "memory");
    __builtin_amdgcn_s_barrier();
    __builtin_amdgcn_sched_barrier(0);
    COMPUTEW(cb);

    // ---- bounce epilogue: two 128-row passes through 64 KiB of LDS ----
#pragma unroll
    for (int half = 0; half < 2; half++) {
        __syncthreads();
        if (wm == half) {
#pragma unroll
            for (int m = 0; m < 8; m++) {
                const int row = m * 16 + lrow;      // local row within half
                const int sw = (row & 7) << 3;
#pragma unroll
                for (int n = 0; n < 4; n++) {
                    const int col = wn * 64 + n * 16 + lq * 4;
                    const float4 b4 = *(const float4*)(bias + bn * 256 + col);
                    float v0 = acc[m][n][0] + b4.x, v1 = acc[m][n][1] + b4.y;
                    float v2 = acc[m][n][2] + b4.z, v3 = acc[m][n][3] + b4.w;
                    if (MODE == 2) {
                        const float g0 = v0 * (0.7978845608f + 0.0356774081f * v0 * v0);
                        const float g1 = v1 * (0.7978845608f + 0.0356774081f * v1 * v1);
                        const float g2 = v2 * (0.7978845608f + 0.0356774081f * v2 * v2);
                        const float g3 = v3 * (0.7978845608f + 0.0356774081f * v3 * v3);
                        v0 /= (1.f + __expf(-2.f * g0)); v1 /= (1.f + __expf(-2.f * g1));
                        v2 /= (1.f + __expf(-2.f * g2)); v3 /= (1.f + __expf(-2.f * g3));
                    }
                    const int cidx = (((col & 127) ^ sw)) | (col & 128);
                    *(ushort4*)(smem + row * 256 + cidx) =
                        make_ushort4(f2bf(v0), f2bf(v1), f2bf(v2), f2bf(v3));
                }
            }
        }
        __syncthreads();
#pragma unroll
        for (int i = 0; i < 8; i++) {
            const int r = i * 16 + (tid >> 5);
            const int c0 = (tid & 31) << 3;
            const int sw = (r & 7) << 3;
            const int cA = ((c0 & 127) ^ sw) | (c0 & 128);
            const uint4 val = *(const uint4*)(smem + r * 256 + cA);
            *(uint4*)(Cb + (size_t)(bm * 256 + half * 128 + r) * Nn + bn * 256 + c0) = val;
        }
    }
#undef COMPUTEW
#undef STAGEW
}

// ---------------- Windowed attention: one block per window (chunked) ----------------
__global__ __launch_bounds__(256) void attn_kernel(const u16* __restrict__ qkv_c,
                                                   const float* __restrict__ relb,
                                                   u16* __restrict__ out,
                                                   int win0) {
    __shared__ __align__(16) u16 kv[WINS * 3 * DIMC];
    __shared__ float S[HEADS][WINS][WINS];
    const int tid = threadIdx.x;
    const int win = win0 + blockIdx.x;
    const u16* src = qkv_c + (size_t)blockIdx.x * (WINS * 3 * DIMC);
    for (int idx = tid * 8; idx < WINS * 3 * DIMC; idx += 2048)
        *(uint4*)(kv + idx) = *(const uint4*)(src + idx);
    __syncthreads();

    const bool lastw = (win % NWIN) == (NWIN - 1);
    for (int e = tid; e < HEADS * WINS * WINS; e += 256) {
        const int hh = e / (WINS * WINS);
        const int rem = e - hh * WINS * WINS;
        const int i = rem / WINS, j = rem - (rem / WINS) * WINS;
        const u16* qp = kv + i * (3 * DIMC) + hh * HD;
        const u16* kp = kv + j * (3 * DIMC) + DIMC + hh * HD;
        float s = 0.f;
#pragma unroll
        for (int c = 0; c < 64; c++) s += bf2f(qp[c]) * bf2f(kp[c]);
        s *= 0.125f;
        s += relb[(i - j + WINS - 1) * HEADS + hh];
        if (lastw && ((i < SHIFT_SZ) != (j < SHIFT_SZ))) s -= 100.f;
        S[hh][i][j] = s;
    }
    __syncthreads();

    if (tid < HEADS * WINS) {
        const int hh = tid / WINS, i = tid - (tid / WINS) * WINS;
        float m = -1e30f;
#pragma unroll
        for (int j = 0; j < WINS; j++) m = fmaxf(m, S[hh][i][j]);
        float e[WINS], sum = 0.f;
#pragma unroll
        for (int j = 0; j < WINS; j++) { e[j] = __expf(S[hh][i][j] - m); sum += e[j]; }
        const float inv = 1.f / sum;
#pragma unroll
        for (int j = 0; j < WINS; j++) S[hh][i][j] = e[j] * inv;
    }
    __syncthreads();

    {
        const int hh = tid >> 5, dl = tid & 31;
#pragma unroll
        for (int half = 0; half < 2; half++) {
            const int d = dl + half * 32;
            float vv[WINS];
#pragma unroll
            for (int j = 0; j < WINS; j++) vv[j] = bf2f(kv[j * (3 * DIMC) + 2 * DIMC + hh * HD + d]);
#pragma unroll
            for (int i = 0; i < WINS; i++) {
                float o = 0.f;
#pragma unroll
                for (int j = 0; j < WINS; j++) o += S[hh][i][j] * vv[j];
                out[(size_t)(win * WINS + i) * DIMC + hh * HD + d] = f2bf(o);
            }
        }
    }
}

extern "C" void kernel_launch(void* const* d_in, const int* in_sizes, int n_in,
                              void* d_out, int out_size, void* d_ws, size_t ws_size,
                              hipStream_t stream) {
    const float* x     = (const float*)d_in[0];
    const float* n1w   = (const float*)d_in[1];
    const float* n1b   = (const float*)d_in[2];
    const float* qkvw  = (const float*)d_in[3];
    const float* qkvb  = (const float*)d_in[4];
    const float* relb  = (const float*)d_in[5];
    const float* projw = (const float*)d_in[6];
    const float* projb = (const float*)d_in[7];
    const float* n2w   = (const float*)d_in[8];
    const float* n2b   = (const float*)d_in[9];
    const float* fc1w  = (const float*)d_in[10];
    const float* fc1b  = (const float*)d_in[11];
    const float* fc2w  = (const float*)d_in[12];
    const float* fc2b  = (const float*)d_in[13];

    float* outp = (float*)d_out;
    char* ws = (char*)d_ws;
    u16* wb_qkv  = (u16*)(ws);
    u16* wb_proj = (u16*)(ws + 1572864);
    u16* wb_fc1  = (u16*)(ws + 2097152);
    u16* wb_fc2  = (u16*)(ws + 4194304);
    u16* r0  = (u16*)(ws + 6291456);
    u16* xb  = (u16*)(ws + 71827456);
    u16* x2b = (u16*)(ws + 137363456);
    u16* big = (u16*)(ws + 202899456);

    cvt_kernel<<<768, 256, 0, stream>>>(qkvw, wb_qkv, 786432);
    cvt_kernel<<<256, 256, 0, stream>>>(projw, wb_proj, 262144);
    cvt_kernel<<<1024, 256, 0, stream>>>(fc1w, wb_fc1, 1048576);
    cvt_kernel<<<1024, 256, 0, stream>>>(fc2w, wb_fc2, 1048576);

    const size_t avail = ws_size > (size_t)202899456 ? ws_size - (size_t)202899456 : 0;
    const int nc1 = (avail >= (size_t)98304000) ? 2
                  : (avail >= (size_t)39321600) ? 5 : (avail >= (size_t)19660800) ? 10 : 50;
    const int nc2 = (avail >= (size_t)131072000) ? 2
                  : (avail >= (size_t)52428800) ? 5 : (avail >= (size_t)26214400) ? 10 : 25;

    // 1) h = LN1(x) rolled by -SHIFT -> r0 ; xb = bf16(x)
    ln_kernel<SHIFT_SZ><<<TOKENS / 4, 256, 0, stream>>>(x, n1w, n1b, r0, xb);

    // 2+3) qkv GEMM (wide) + windowed attention, chunked
    const int rows1 = TOKENS / nc1;
    for (int c = 0; c < nc1; ++c) {
        const int row0 = c * rows1;
        gemm_w<0><<<(rows1 / 256) * 6, 512, 0, stream>>>(
            r0 + (size_t)row0 * DIMC, wb_qkv, qkvb, big, 1536, DIMC, 6);
        attn_kernel<<<rows1 / WINS, 256, 0, stream>>>(big, relb, r0, row0 / WINS);
    }

    // 4) x2b = bf16( xb + roll(attn_out @ proj_w^T + proj_b, +SHIFT) )
    gemm_bt<1><<<(TOKENS / 256) * 4, 256, 0, stream>>>(
        r0, wb_proj, projb, x2b, nullptr, xb, DIMC, DIMC, 4);

    // 5) h2 = LN2(x2b) -> r0
    ln_kernel_bf<<<TOKENS / 4, 256, 0, stream>>>(x2b, n2w, n2b, r0);

    // 6+7) MLP chunked: g = gelu(h2 @ fc1^T) (wide); out = x2b + g @ fc2^T (fp32)
    const int rows2 = TOKENS / nc2;
    for (int c = 0; c < nc2; ++c) {
        const int row0 = c * rows2;
        gemm_w<2><<<(rows2 / 256) * 8, 512, 0, stream>>>(
            r0 + (size_t)row0 * DIMC, wb_fc1, fc1b, big, HIDDEN, DIMC, 8);
        gemm_bt<3><<<(rows2 / 256) * 4, 256, 0, stream>>>(
            big, wb_fc2, fc2b, nullptr, outp + (size_t)row0 * DIMC,
            x2b + (size_t)row0 * DIMC, DIMC, HIDDEN, 4);
    }
}

// Round 17
// 757.029 us; speedup vs baseline: 1.0819x; 1.0819x over previous
//
#include <hip/hip_runtime.h>

#define DIMC 512
#define HEADS 8
#define HD 64
#define WINS 10
#define SHIFT_SZ 5
#define FRAMES 1000
#define NWIN 100
#define BATCH 64
#define TOKENS 64000
#define HIDDEN 2048

typedef unsigned short u16;
typedef __attribute__((ext_vector_type(8))) short bf16x8;
typedef __attribute__((ext_vector_type(4))) float f32x4;

__device__ __forceinline__ float bf2f(u16 u) { return __uint_as_float(((unsigned)u) << 16); }
__device__ __forceinline__ u16 f2bf(float f) {
    unsigned u = __float_as_uint(f);
    u += 0x7fffu + ((u >> 16) & 1u);
    return (u16)(u >> 16);
}

// ---------------- fused fp32 -> bf16 conversion of all 4 weight matrices ----------------
// sizes: qkv 786432 | proj 262144 | fc1 1048576 | fc2 1048576  (total 3145728)
__global__ __launch_bounds__(256) void cvt4_kernel(const float* __restrict__ s0,
                                                   const float* __restrict__ s1,
                                                   const float* __restrict__ s2,
                                                   const float* __restrict__ s3,
                                                   u16* __restrict__ d0, u16* __restrict__ d1,
                                                   u16* __restrict__ d2, u16* __restrict__ d3) {
    const int i = (blockIdx.x * 256 + threadIdx.x) * 4;
    const float* s; u16* d; int off;
    if (i < 786432)       { s = s0; d = d0; off = i; }
    else if (i < 1048576) { s = s1; d = d1; off = i - 786432; }
    else if (i < 2097152) { s = s2; d = d2; off = i - 1048576; }
    else                  { s = s3; d = d3; off = i - 2097152; }
    const float4 v = *(const float4*)(s + off);
    *(ushort4*)(d + off) = make_ushort4(f2bf(v.x), f2bf(v.y), f2bf(v.z), f2bf(v.w));
}

// ---------------- LayerNorm fp32-in: bf16 out rolled by -SH ----------------
template <int SH>
__global__ __launch_bounds__(256) void ln_kernel(const float* __restrict__ x,
                                                 const float* __restrict__ w,
                                                 const float* __restrict__ b,
                                                 u16* __restrict__ out) {
    const int wave = threadIdx.x >> 6, lane = threadIdx.x & 63;
    const int row = blockIdx.x * 4 + wave;
    const float4* rp = (const float4*)(x + (size_t)row * DIMC);
    const float4 v0 = rp[lane];
    const float4 v1 = rp[64 + lane];
    float f[8] = {v0.x, v0.y, v0.z, v0.w, v1.x, v1.y, v1.z, v1.w};
    float sum = 0.f, sq = 0.f;
#pragma unroll
    for (int i = 0; i < 8; i++) { sum += f[i]; sq += f[i] * f[i]; }
#pragma unroll
    for (int off = 32; off >= 1; off >>= 1) {
        sum += __shfl_xor(sum, off);
        sq += __shfl_xor(sq, off);
    }
    const float mean = sum * (1.f / DIMC);
    const float var = sq * (1.f / DIMC) - mean * mean;
    const float rstd = rsqrtf(var + 1e-5f);

    const float4 w0 = ((const float4*)w)[lane], w1 = ((const float4*)w)[64 + lane];
    const float4 b0 = ((const float4*)b)[lane], b1 = ((const float4*)b)[64 + lane];
    const float wf[8] = {w0.x, w0.y, w0.z, w0.w, w1.x, w1.y, w1.z, w1.w};
    const float bf[8] = {b0.x, b0.y, b0.z, b0.w, b1.x, b1.y, b1.z, b1.w};
    u16 o[8];
#pragma unroll
    for (int i = 0; i < 8; i++) o[i] = f2bf((f[i] - mean) * rstd * wf[i] + bf[i]);

    int dst = row;
    if (SH) {
        int bb = row / FRAMES;
        int t = row - bb * FRAMES;
        int td = t - SH; if (td < 0) td += FRAMES;
        dst = bb * FRAMES + td;
    }
    u16* op = out + (size_t)dst * DIMC;
    *(ushort4*)(op + 4 * lane) = make_ushort4(o[0], o[1], o[2], o[3]);
    *(ushort4*)(op + 256 + 4 * lane) = make_ushort4(o[4], o[5], o[6], o[7]);
}

// ---------------- LayerNorm bf16-in (for LN2 over x2b) ----------------
__global__ __launch_bounds__(256) void ln_kernel_bf(const u16* __restrict__ x,
                                                    const float* __restrict__ w,
                                                    const float* __restrict__ b,
                                                    u16* __restrict__ out) {
    const int wave = threadIdx.x >> 6, lane = threadIdx.x & 63;
    const int row = blockIdx.x * 4 + wave;
    const uint4 v = ((const uint4*)(x + (size_t)row * DIMC))[lane];
    const unsigned uv[4] = {v.x, v.y, v.z, v.w};
    float f[8];
    float sum = 0.f, sq = 0.f;
#pragma unroll
    for (int i = 0; i < 4; i++) {
        float a = __uint_as_float(uv[i] << 16);
        float c = __uint_as_float(uv[i] & 0xffff0000u);
        f[2 * i] = a; f[2 * i + 1] = c;
        sum += a + c; sq += a * a + c * c;
    }
#pragma unroll
    for (int off = 32; off >= 1; off >>= 1) {
        sum += __shfl_xor(sum, off);
        sq += __shfl_xor(sq, off);
    }
    const float mean = sum * (1.f / DIMC);
    const float var = sq * (1.f / DIMC) - mean * mean;
    const float rstd = rsqrtf(var + 1e-5f);

    const float4 w0 = ((const float4*)w)[2 * lane], w1 = ((const float4*)w)[2 * lane + 1];
    const float4 b0 = ((const float4*)b)[2 * lane], b1 = ((const float4*)b)[2 * lane + 1];
    const float wf[8] = {w0.x, w0.y, w0.z, w0.w, w1.x, w1.y, w1.z, w1.w};
    const float bf[8] = {b0.x, b0.y, b0.z, b0.w, b1.x, b1.y, b1.z, b1.w};
    u16 o[8];
#pragma unroll
    for (int i = 0; i < 8; i++) o[i] = f2bf((f[i] - mean) * rstd * wf[i] + bf[i]);
    uint4 ov;
    ov.x = (unsigned)o[0] | ((unsigned)o[1] << 16);
    ov.y = (unsigned)o[2] | ((unsigned)o[3] << 16);
    ov.z = (unsigned)o[4] | ((unsigned)o[5] << 16);
    ov.w = (unsigned)o[6] | ((unsigned)o[7] << 16);
    ((uint4*)(out + (size_t)row * DIMC))[lane] = ov;
}

// ---------------- GEMM: C = A[M,K](bf16) * W[Nn,K](bf16)^T + bias ----------------
// R13-verified structure (best: 767.7 us): 256x128 tile, 4 waves, acc[8][4];
// BK=32, 3-buffer rotating LDS (72 KiB, 2 blocks/CU), counted s_waitcnt vmcnt(6)
// + raw s_barrier (T4), T1 XCD remap, T2 granule-XOR, swizzled-LDS bounce
// epilogue for bf16 MODEs, COMPUTE-then-STAGE order.
// MODE 0: bf16 out (qkv). MODE 2: fc1 + fast GELU, bf16 out.
// MODE 1: proj -> x2b bf16 at rolled rows, += fp32 x residual (read rolled).
// MODE 3: fc2 -> fp32 out, += bf16 x2b residual (direct stores).
#define GLD16(gp, lp)                                                                     \
    __builtin_amdgcn_global_load_lds((const __attribute__((address_space(1))) void*)(gp), \
                                     (__attribute__((address_space(3))) void*)(lp), 16, 0, 0)

template <int MODE>
__global__ __launch_bounds__(256, 2) void gemm_bt(const u16* __restrict__ A,
                                                  const u16* __restrict__ W,
                                                  const float* __restrict__ bias,
                                                  u16* __restrict__ Cb,
                                                  float* __restrict__ Cf,
                                                  const float* __restrict__ Rf,
                                                  const u16* __restrict__ Rb,
                                                  int Nn, int K, int nbn) {
    __shared__ __align__(16) u16 smem[36864];
    const int tid = threadIdx.x;
    const int w = tid >> 6, l = tid & 63;

    const int nwg = gridDim.x;
    const int q8 = nwg >> 3, r8 = nwg & 7;
    const int xcd = blockIdx.x & 7, bidx = blockIdx.x >> 3;
    const int swz = (xcd < r8 ? xcd * (q8 + 1) : r8 * (q8 + 1) + (xcd - r8) * q8) + bidx;
    const int bm = swz / nbn, bn = swz - bm * nbn;

    const int wr = w >> 1, wc = w & 1;
    const int lrow = l & 15, lq = l >> 4;

    f32x4 acc[8][4];
#pragma unroll
    for (int m = 0; m < 8; m++)
#pragma unroll
        for (int n = 0; n < 4; n++) acc[m][n] = (f32x4)0.0f;

    const int gsrc8 = (((tid & 3) ^ ((tid >> 3) & 3)) << 3);
    const u16* Ag = A + (size_t)(bm * 256 + (tid >> 2)) * K + gsrc8;
    const u16* Bg = W + (size_t)(bn * 128 + (tid >> 2)) * K + gsrc8;
    const size_t rowoff = (size_t)64 * K;
    const int lb = w * 512;

#define STAGE(buf, kt) do {                                       \
        u16* sb_ = smem + (buf) * 12288;                          \
        GLD16(Ag + (kt), sb_ + lb);                               \
        GLD16(Ag + rowoff + (kt), sb_ + 2048 + lb);               \
        GLD16(Ag + 2 * rowoff + (kt), sb_ + 4096 + lb);           \
        GLD16(Ag + 3 * rowoff + (kt), sb_ + 6144 + lb);           \
        GLD16(Bg + (kt), sb_ + 8192 + lb);                        \
        GLD16(Bg + rowoff + (kt), sb_ + 10240 + lb);              \
    } while (0)

    const int gran = ((lq ^ ((lrow >> 1) & 3)) << 3);
    const int arow = (wr * 128 + lrow) * 32 + gran;
    const int brow = 8192 + (wc * 64 + lrow) * 32 + gran;

#define COMPUTE(buf) do {                                                          \
        const u16* sb = smem + (buf) * 12288;                                      \
        bf16x8 bv[4];                                                              \
        _Pragma("unroll")                                                          \
        for (int n = 0; n < 4; n++) bv[n] = *(const bf16x8*)(sb + brow + n * 512); \
        _Pragma("unroll")                                                          \
        for (int m = 0; m < 8; m++) {                                              \
            const bf16x8 af = *(const bf16x8*)(sb + arow + m * 512);               \
            _Pragma("unroll")                                                      \
            for (int n = 0; n < 4; n++)   /* SWAPPED -> C^T fragments */           \
                acc[m][n] = __builtin_amdgcn_mfma_f32_16x16x32_bf16(bv[n], af, acc[m][n], 0, 0, 0); \
        }                                                                          \
    } while (0)

    const int nt = K >> 5;
    STAGE(0, 0);
    STAGE(1, 32);
    int cb = 0;
    for (int t = 0; t < nt - 1; ++t) {
        asm volatile("s_waitcnt vmcnt(6)" ::: "memory");
        __builtin_amdgcn_s_barrier();
        __builtin_amdgcn_sched_barrier(0);
        COMPUTE(cb);
        if (t + 2 < nt) {
            const int sbuf = cb == 0 ? 2 : cb - 1;   // (t+2) % 3
            STAGE(sbuf, (t + 2) * 32);
        }
        cb = cb == 2 ? 0 : cb + 1;
    }
    asm volatile("s_waitcnt vmcnt(0)" ::: "memory");
    __builtin_amdgcn_s_barrier();
    __builtin_amdgcn_sched_barrier(0);
    COMPUTE(cb);

    if (MODE == 0 || MODE == 1 || MODE == 2) {
        // ---- bf16 bounce epilogue: acc -> swizzled LDS -> coalesced stores ----
        __syncthreads();
#pragma unroll
        for (int m = 0; m < 8; m++) {
            const int row = wr * 128 + m * 16 + lrow;
            const int sw = (row & 7) << 3;
#pragma unroll
            for (int n = 0; n < 4; n++) {
                const int col = wc * 64 + n * 16 + lq * 4;
                const float4 b4 = *(const float4*)(bias + bn * 128 + col);
                float v0 = acc[m][n][0] + b4.x, v1 = acc[m][n][1] + b4.y;
                float v2 = acc[m][n][2] + b4.z, v3 = acc[m][n][3] + b4.w;
                if (MODE == 2) {
                    const float g0 = v0 * (0.7978845608f + 0.0356774081f * v0 * v0);
                    const float g1 = v1 * (0.7978845608f + 0.0356774081f * v1 * v1);
                    const float g2 = v2 * (0.7978845608f + 0.0356774081f * v2 * v2);
                    const float g3 = v3 * (0.7978845608f + 0.0356774081f * v3 * v3);
                    v0 /= (1.f + __expf(-2.f * g0)); v1 /= (1.f + __expf(-2.f * g1));
                    v2 /= (1.f + __expf(-2.f * g2)); v3 /= (1.f + __expf(-2.f * g3));
                }
                *(ushort4*)(smem + row * 128 + ((col ^ sw))) =
                    make_ushort4(f2bf(v0), f2bf(v1), f2bf(v2), f2bf(v3));
            }
        }
        __syncthreads();
        const int c8 = lrow * 8;
#pragma unroll
        for (int i = 0; i < 16; i++) {
            const int r = w * 64 + i * 4 + lq;
            const uint4 val = *(const uint4*)(smem + r * 128 + (c8 ^ ((r & 7) << 3)));
            const int grow = bm * 256 + r;
            if (MODE == 1) {
                int bb = grow / FRAMES;
                int tr = grow - bb * FRAMES;
                int td = tr + SHIFT_SZ; if (td >= FRAMES) td -= FRAMES;
                const size_t dr = (size_t)(bb * FRAMES + td) * DIMC + bn * 128 + c8;
                const float4 rA = *(const float4*)(Rf + dr);
                const float4 rB = *(const float4*)(Rf + dr + 4);
                const u16* vp = (const u16*)&val;
                u16 o[8];
                o[0] = f2bf(bf2f(vp[0]) + rA.x); o[1] = f2bf(bf2f(vp[1]) + rA.y);
                o[2] = f2bf(bf2f(vp[2]) + rA.z); o[3] = f2bf(bf2f(vp[3]) + rA.w);
                o[4] = f2bf(bf2f(vp[4]) + rB.x); o[5] = f2bf(bf2f(vp[5]) + rB.y);
                o[6] = f2bf(bf2f(vp[6]) + rB.z); o[7] = f2bf(bf2f(vp[7]) + rB.w);
                uint4 ov;
                ov.x = (unsigned)o[0] | ((unsigned)o[1] << 16);
                ov.y = (unsigned)o[2] | ((unsigned)o[3] << 16);
                ov.z = (unsigned)o[4] | ((unsigned)o[5] << 16);
                ov.w = (unsigned)o[6] | ((unsigned)o[7] << 16);
                *(uint4*)(Cb + dr) = ov;
            } else {
                *(uint4*)(Cb + (size_t)grow * Nn + bn * 128 + c8) = val;
            }
        }
    } else {
        // ---- MODE 3: fp32 direct with bf16 residual ----
#pragma unroll
        for (int m = 0; m < 8; m++) {
            const int grow = bm * 256 + wr * 128 + m * 16 + lrow;
#pragma unroll
            for (int n = 0; n < 4; n++) {
                const int gcb = bn * 128 + wc * 64 + n * 16 + lq * 4;
                const float4 b4 = *(const float4*)(bias + gcb);
                const size_t dr = (size_t)grow * Nn + gcb;
                const ushort4 rb = *(const ushort4*)(Rb + dr);
                float4 o;
                o.x = acc[m][n][0] + b4.x + bf2f(rb.x);
                o.y = acc[m][n][1] + b4.y + bf2f(rb.y);
                o.z = acc[m][n][2] + b4.z + bf2f(rb.z);
                o.w = acc[m][n][3] + b4.w + bf2f(rb.w);
                *(float4*)(Cf + dr) = o;
            }
        }
    }
#undef COMPUTE
#undef STAGE
}

// ---------------- Windowed attention: one block per window (chunked) ----------------
__global__ __launch_bounds__(256) void attn_kernel(const u16* __restrict__ qkv_c,
                                                   const float* __restrict__ relb,
                                                   u16* __restrict__ out,
                                                   int win0) {
    __shared__ __align__(16) u16 kv[WINS * 3 * DIMC];  // 30720 B
    __shared__ float S[HEADS][WINS][WINS];
    const int tid = threadIdx.x;
    const int win = win0 + blockIdx.x;
    const u16* src = qkv_c + (size_t)blockIdx.x * (WINS * 3 * DIMC);
    for (int idx = tid * 8; idx < WINS * 3 * DIMC; idx += 2048)
        *(uint4*)(kv + idx) = *(const uint4*)(src + idx);
    __syncthreads();

    const bool lastw = (win % NWIN) == (NWIN - 1);
    for (int e = tid; e < HEADS * WINS * WINS; e += 256) {
        const int hh = e / (WINS * WINS);
        const int rem = e - hh * WINS * WINS;
        const int i = rem / WINS, j = rem - (rem / WINS) * WINS;
        const u16* qp = kv + i * (3 * DIMC) + hh * HD;
        const u16* kp = kv + j * (3 * DIMC) + DIMC + hh * HD;
        float s = 0.f;
#pragma unroll
        for (int c = 0; c < 64; c++) s += bf2f(qp[c]) * bf2f(kp[c]);
        s *= 0.125f;
        s += relb[(i - j + WINS - 1) * HEADS + hh];
        if (lastw && ((i < SHIFT_SZ) != (j < SHIFT_SZ))) s -= 100.f;
        S[hh][i][j] = s;
    }
    __syncthreads();

    if (tid < HEADS * WINS) {
        const int hh = tid / WINS, i = tid - (tid / WINS) * WINS;
        float m = -1e30f;
#pragma unroll
        for (int j = 0; j < WINS; j++) m = fmaxf(m, S[hh][i][j]);
        float e[WINS], sum = 0.f;
#pragma unroll
        for (int j = 0; j < WINS; j++) { e[j] = __expf(S[hh][i][j] - m); sum += e[j]; }
        const float inv = 1.f / sum;
#pragma unroll
        for (int j = 0; j < WINS; j++) S[hh][i][j] = e[j] * inv;
    }
    __syncthreads();

    {
        const int hh = tid >> 5, dl = tid & 31;
#pragma unroll
        for (int half = 0; half < 2; half++) {
            const int d = dl + half * 32;
            float vv[WINS];
#pragma unroll
            for (int j = 0; j < WINS; j++) vv[j] = bf2f(kv[j * (3 * DIMC) + 2 * DIMC + hh * HD + d]);
#pragma unroll
            for (int i = 0; i < WINS; i++) {
                float o = 0.f;
#pragma unroll
                for (int j = 0; j < WINS; j++) o += S[hh][i][j] * vv[j];
                out[(size_t)(win * WINS + i) * DIMC + hh * HD + d] = f2bf(o);
            }
        }
    }
}

extern "C" void kernel_launch(void* const* d_in, const int* in_sizes, int n_in,
                              void* d_out, int out_size, void* d_ws, size_t ws_size,
                              hipStream_t stream) {
    const float* x     = (const float*)d_in[0];
    const float* n1w   = (const float*)d_in[1];
    const float* n1b   = (const float*)d_in[2];
    const float* qkvw  = (const float*)d_in[3];
    const float* qkvb  = (const float*)d_in[4];
    const float* relb  = (const float*)d_in[5];
    const float* projw = (const float*)d_in[6];
    const float* projb = (const float*)d_in[7];
    const float* n2w   = (const float*)d_in[8];
    const float* n2b   = (const float*)d_in[9];
    const float* fc1w  = (const float*)d_in[10];
    const float* fc1b  = (const float*)d_in[11];
    const float* fc2w  = (const float*)d_in[12];
    const float* fc2b  = (const float*)d_in[13];

    float* outp = (float*)d_out;       // final fp32 output (written once, by fc2)
    char* ws = (char*)d_ws;
    u16* wb_qkv  = (u16*)(ws);
    u16* wb_proj = (u16*)(ws + 1572864);
    u16* wb_fc1  = (u16*)(ws + 2097152);
    u16* wb_fc2  = (u16*)(ws + 4194304);
    u16* r0  = (u16*)(ws + 6291456);    // 65.536 MB: h -> attn_out -> h2 (bf16)
    u16* x2b = (u16*)(ws + 71827456);   // 65.536 MB: x2 in bf16
    u16* big = (u16*)(ws + 137363456);  // chunked qkv / fc1-activation (bf16)

    // 0) all weights fp32 -> bf16 in ONE dispatch (was 4 serialized tiny kernels)
    cvt4_kernel<<<3072, 256, 0, stream>>>(qkvw, projw, fc1w, fc2w,
                                          wb_qkv, wb_proj, wb_fc1, wb_fc2);

    const size_t avail = ws_size > (size_t)137363456 ? ws_size - (size_t)137363456 : 0;
    // qkv chunk rows: multiple of lcm(256 tile, 10 window) = 1280
    const int nc1 = (avail >= (size_t)98304000) ? 2
                  : (avail >= (size_t)39321600) ? 5 : (avail >= (size_t)19660800) ? 10 : 50;
    // mlp chunk rows: multiple of 256
    const int nc2 = (avail >= (size_t)131072000) ? 2
                  : (avail >= (size_t)52428800) ? 5 : (avail >= (size_t)26214400) ? 10 : 25;

    // 1) h = LN1(x), rolled by -SHIFT
    ln_kernel<SHIFT_SZ><<<TOKENS / 4, 256, 0, stream>>>(x, n1w, n1b, r0);

    // 2+3) qkv GEMM + windowed attention, chunked
    const int rows1 = TOKENS / nc1;
    for (int c = 0; c < nc1; ++c) {
        const int row0 = c * rows1;
        gemm_bt<0><<<(rows1 / 256) * 12, 256, 0, stream>>>(
            r0 + (size_t)row0 * DIMC, wb_qkv, qkvb, big, nullptr, nullptr, nullptr, 1536, DIMC, 12);
        attn_kernel<<<rows1 / WINS, 256, 0, stream>>>(big, relb, r0, row0 / WINS);
    }

    // 4) x2b = bf16( x + roll(attn_out @ proj_w^T + proj_b, +SHIFT) )
    gemm_bt<1><<<(TOKENS / 256) * 4, 256, 0, stream>>>(
        r0, wb_proj, projb, x2b, nullptr, x, nullptr, DIMC, DIMC, 4);

    // 5) h2 = LN2(x2b) -> r0
    ln_kernel_bf<<<TOKENS / 4, 256, 0, stream>>>(x2b, n2w, n2b, r0);

    // 6+7) MLP chunked: g = gelu(h2 @ fc1^T); out = x2b + g @ fc2^T (fp32)
    const int rows2 = TOKENS / nc2;
    for (int c = 0; c < nc2; ++c) {
        const int row0 = c * rows2;
        gemm_bt<2><<<(rows2 / 256) * 16, 256, 0, stream>>>(
            r0 + (size_t)row0 * DIMC, wb_fc1, fc1b, big, nullptr, nullptr, nullptr, HIDDEN, DIMC, 16);
        gemm_bt<3><<<(rows2 / 256) * 4, 256, 0, stream>>>(
            big, wb_fc2, fc2b, nullptr, outp + (size_t)row0 * DIMC, nullptr,
            x2b + (size_t)row0 * DIMC, DIMC, HIDDEN, 4);
    }
}

// Round 18
// 739.086 us; speedup vs baseline: 1.1081x; 1.0243x over previous
//
#include <hip/hip_runtime.h>

#define DIMC 512
#define HEADS 8
#define HD 64
#define WINS 10
#define SHIFT_SZ 5
#define FRAMES 1000
#define NWIN 100
#define BATCH 64
#define TOKENS 64000
#define HIDDEN 2048

typedef unsigned short u16;
typedef __attribute__((ext_vector_type(8))) short bf16x8;
typedef __attribute__((ext_vector_type(4))) float f32x4;

__device__ __forceinline__ float bf2f(u16 u) { return __uint_as_float(((unsigned)u) << 16); }
__device__ __forceinline__ u16 f2bf(float f) {
    unsigned u = __float_as_uint(f);
    u += 0x7fffu + ((u >> 16) & 1u);
    return (u16)(u >> 16);
}

// ---------------- fused fp32 -> bf16 conversion of all 4 weight matrices ----------------
__global__ __launch_bounds__(256) void cvt4_kernel(const float* __restrict__ s0,
                                                   const float* __restrict__ s1,
                                                   const float* __restrict__ s2,
                                                   const float* __restrict__ s3,
                                                   u16* __restrict__ d0, u16* __restrict__ d1,
                                                   u16* __restrict__ d2, u16* __restrict__ d3) {
    const int i = (blockIdx.x * 256 + threadIdx.x) * 4;
    const float* s; u16* d; int off;
    if (i < 786432)       { s = s0; d = d0; off = i; }
    else if (i < 1048576) { s = s1; d = d1; off = i - 786432; }
    else if (i < 2097152) { s = s2; d = d2; off = i - 1048576; }
    else                  { s = s3; d = d3; off = i - 2097152; }
    const float4 v = *(const float4*)(s + off);
    *(ushort4*)(d + off) = make_ushort4(f2bf(v.x), f2bf(v.y), f2bf(v.z), f2bf(v.w));
}

// ---------------- LayerNorm fp32-in: bf16 out rolled by -SH ----------------
template <int SH>
__global__ __launch_bounds__(256) void ln_kernel(const float* __restrict__ x,
                                                 const float* __restrict__ w,
                                                 const float* __restrict__ b,
                                                 u16* __restrict__ out) {
    const int wave = threadIdx.x >> 6, lane = threadIdx.x & 63;
    const int row = blockIdx.x * 4 + wave;
    const float4* rp = (const float4*)(x + (size_t)row * DIMC);
    const float4 v0 = rp[lane];
    const float4 v1 = rp[64 + lane];
    float f[8] = {v0.x, v0.y, v0.z, v0.w, v1.x, v1.y, v1.z, v1.w};
    float sum = 0.f, sq = 0.f;
#pragma unroll
    for (int i = 0; i < 8; i++) { sum += f[i]; sq += f[i] * f[i]; }
#pragma unroll
    for (int off = 32; off >= 1; off >>= 1) {
        sum += __shfl_xor(sum, off);
        sq += __shfl_xor(sq, off);
    }
    const float mean = sum * (1.f / DIMC);
    const float var = sq * (1.f / DIMC) - mean * mean;
    const float rstd = rsqrtf(var + 1e-5f);

    const float4 w0 = ((const float4*)w)[lane], w1 = ((const float4*)w)[64 + lane];
    const float4 b0 = ((const float4*)b)[lane], b1 = ((const float4*)b)[64 + lane];
    const float wf[8] = {w0.x, w0.y, w0.z, w0.w, w1.x, w1.y, w1.z, w1.w};
    const float bf[8] = {b0.x, b0.y, b0.z, b0.w, b1.x, b1.y, b1.z, b1.w};
    u16 o[8];
#pragma unroll
    for (int i = 0; i < 8; i++) o[i] = f2bf((f[i] - mean) * rstd * wf[i] + bf[i]);

    int dst = row;
    if (SH) {
        int bb = row / FRAMES;
        int t = row - bb * FRAMES;
        int td = t - SH; if (td < 0) td += FRAMES;
        dst = bb * FRAMES + td;
    }
    u16* op = out + (size_t)dst * DIMC;
    *(ushort4*)(op + 4 * lane) = make_ushort4(o[0], o[1], o[2], o[3]);
    *(ushort4*)(op + 256 + 4 * lane) = make_ushort4(o[4], o[5], o[6], o[7]);
}

// ---------------- LayerNorm bf16-in (for LN2 over x2b) ----------------
__global__ __launch_bounds__(256) void ln_kernel_bf(const u16* __restrict__ x,
                                                    const float* __restrict__ w,
                                                    const float* __restrict__ b,
                                                    u16* __restrict__ out) {
    const int wave = threadIdx.x >> 6, lane = threadIdx.x & 63;
    const int row = blockIdx.x * 4 + wave;
    const uint4 v = ((const uint4*)(x + (size_t)row * DIMC))[lane];
    const unsigned uv[4] = {v.x, v.y, v.z, v.w};
    float f[8];
    float sum = 0.f, sq = 0.f;
#pragma unroll
    for (int i = 0; i < 4; i++) {
        float a = __uint_as_float(uv[i] << 16);
        float c = __uint_as_float(uv[i] & 0xffff0000u);
        f[2 * i] = a; f[2 * i + 1] = c;
        sum += a + c; sq += a * a + c * c;
    }
#pragma unroll
    for (int off = 32; off >= 1; off >>= 1) {
        sum += __shfl_xor(sum, off);
        sq += __shfl_xor(sq, off);
    }
    const float mean = sum * (1.f / DIMC);
    const float var = sq * (1.f / DIMC) - mean * mean;
    const float rstd = rsqrtf(var + 1e-5f);

    const float4 w0 = ((const float4*)w)[2 * lane], w1 = ((const float4*)w)[2 * lane + 1];
    const float4 b0 = ((const float4*)b)[2 * lane], b1 = ((const float4*)b)[2 * lane + 1];
    const float wf[8] = {w0.x, w0.y, w0.z, w0.w, w1.x, w1.y, w1.z, w1.w};
    const float bf[8] = {b0.x, b0.y, b0.z, b0.w, b1.x, b1.y, b1.z, b1.w};
    u16 o[8];
#pragma unroll
    for (int i = 0; i < 8; i++) o[i] = f2bf((f[i] - mean) * rstd * wf[i] + bf[i]);
    uint4 ov;
    ov.x = (unsigned)o[0] | ((unsigned)o[1] << 16);
    ov.y = (unsigned)o[2] | ((unsigned)o[3] << 16);
    ov.z = (unsigned)o[4] | ((unsigned)o[5] << 16);
    ov.w = (unsigned)o[6] | ((unsigned)o[7] << 16);
    ((uint4*)(out + (size_t)row * DIMC))[lane] = ov;
}

// ---------------- GEMM: C = A[M,K](bf16) * W[Nn,K](bf16)^T + bias ----------------
// R13-verified K-loop: 256x128 tile, 4 waves, acc[8][4]; BK=32, 3-buffer rotating
// LDS (72 KiB, 2 blocks/CU), counted s_waitcnt vmcnt(6) + raw s_barrier (T4),
// T1 XCD remap, T2 granule-XOR. Epilogues (this round): MODE 2 uses cheap
// sigmoid-GELU; MODE 3 adds fp32 LDS bounce (scatter stores cost 1.7x BW, R12/13).
#define GLD16(gp, lp)                                                                     \
    __builtin_amdgcn_global_load_lds((const __attribute__((address_space(1))) void*)(gp), \
                                     (__attribute__((address_space(3))) void*)(lp), 16, 0, 0)

template <int MODE>
__global__ __launch_bounds__(256, 2) void gemm_bt(const u16* __restrict__ A,
                                                  const u16* __restrict__ W,
                                                  const float* __restrict__ bias,
                                                  u16* __restrict__ Cb,
                                                  float* __restrict__ Cf,
                                                  const float* __restrict__ Rf,
                                                  const u16* __restrict__ Rb,
                                                  int Nn, int K, int nbn) {
    __shared__ __align__(16) u16 smem[36864];
    const int tid = threadIdx.x;
    const int w = tid >> 6, l = tid & 63;

    const int nwg = gridDim.x;
    const int q8 = nwg >> 3, r8 = nwg & 7;
    const int xcd = blockIdx.x & 7, bidx = blockIdx.x >> 3;
    const int swz = (xcd < r8 ? xcd * (q8 + 1) : r8 * (q8 + 1) + (xcd - r8) * q8) + bidx;
    const int bm = swz / nbn, bn = swz - bm * nbn;

    const int wr = w >> 1, wc = w & 1;
    const int lrow = l & 15, lq = l >> 4;

    f32x4 acc[8][4];
#pragma unroll
    for (int m = 0; m < 8; m++)
#pragma unroll
        for (int n = 0; n < 4; n++) acc[m][n] = (f32x4)0.0f;

    const int gsrc8 = (((tid & 3) ^ ((tid >> 3) & 3)) << 3);
    const u16* Ag = A + (size_t)(bm * 256 + (tid >> 2)) * K + gsrc8;
    const u16* Bg = W + (size_t)(bn * 128 + (tid >> 2)) * K + gsrc8;
    const size_t rowoff = (size_t)64 * K;
    const int lb = w * 512;

#define STAGE(buf, kt) do {                                       \
        u16* sb_ = smem + (buf) * 12288;                          \
        GLD16(Ag + (kt), sb_ + lb);                               \
        GLD16(Ag + rowoff + (kt), sb_ + 2048 + lb);               \
        GLD16(Ag + 2 * rowoff + (kt), sb_ + 4096 + lb);           \
        GLD16(Ag + 3 * rowoff + (kt), sb_ + 6144 + lb);           \
        GLD16(Bg + (kt), sb_ + 8192 + lb);                        \
        GLD16(Bg + rowoff + (kt), sb_ + 10240 + lb);              \
    } while (0)

    const int gran = ((lq ^ ((lrow >> 1) & 3)) << 3);
    const int arow = (wr * 128 + lrow) * 32 + gran;
    const int brow = 8192 + (wc * 64 + lrow) * 32 + gran;

#define COMPUTE(buf) do {                                                          \
        const u16* sb = smem + (buf) * 12288;                                      \
        bf16x8 bv[4];                                                              \
        _Pragma("unroll")                                                          \
        for (int n = 0; n < 4; n++) bv[n] = *(const bf16x8*)(sb + brow + n * 512); \
        _Pragma("unroll")                                                          \
        for (int m = 0; m < 8; m++) {                                              \
            const bf16x8 af = *(const bf16x8*)(sb + arow + m * 512);               \
            _Pragma("unroll")                                                      \
            for (int n = 0; n < 4; n++)   /* SWAPPED -> C^T fragments */           \
                acc[m][n] = __builtin_amdgcn_mfma_f32_16x16x32_bf16(bv[n], af, acc[m][n], 0, 0, 0); \
        }                                                                          \
    } while (0)

    const int nt = K >> 5;
    STAGE(0, 0);
    STAGE(1, 32);
    int cb = 0;
    for (int t = 0; t < nt - 1; ++t) {
        asm volatile("s_waitcnt vmcnt(6)" ::: "memory");
        __builtin_amdgcn_s_barrier();
        __builtin_amdgcn_sched_barrier(0);
        COMPUTE(cb);
        if (t + 2 < nt) {
            const int sbuf = cb == 0 ? 2 : cb - 1;   // (t+2) % 3
            STAGE(sbuf, (t + 2) * 32);
        }
        cb = cb == 2 ? 0 : cb + 1;
    }
    asm volatile("s_waitcnt vmcnt(0)" ::: "memory");
    __builtin_amdgcn_s_barrier();
    __builtin_amdgcn_sched_barrier(0);
    COMPUTE(cb);

    if (MODE == 0 || MODE == 1 || MODE == 2) {
        // ---- bf16 bounce epilogue: acc -> swizzled LDS -> coalesced stores ----
        __syncthreads();
#pragma unroll
        for (int m = 0; m < 8; m++) {
            const int row = wr * 128 + m * 16 + lrow;
            const int sw = (row & 7) << 3;
#pragma unroll
            for (int n = 0; n < 4; n++) {
                const int col = wc * 64 + n * 16 + lq * 4;
                const float4 b4 = *(const float4*)(bias + bn * 128 + col);
                float v0 = acc[m][n][0] + b4.x, v1 = acc[m][n][1] + b4.y;
                float v2 = acc[m][n][2] + b4.z, v3 = acc[m][n][3] + b4.w;
                if (MODE == 2) {
                    // gelu(v) ~= v * sigmoid(1.702 v)  (cheap; |err|<=0.02)
                    v0 /= (1.f + __expf(-1.702f * v0));
                    v1 /= (1.f + __expf(-1.702f * v1));
                    v2 /= (1.f + __expf(-1.702f * v2));
                    v3 /= (1.f + __expf(-1.702f * v3));
                }
                *(ushort4*)(smem + row * 128 + ((col ^ sw))) =
                    make_ushort4(f2bf(v0), f2bf(v1), f2bf(v2), f2bf(v3));
            }
        }
        __syncthreads();
        const int c8 = lrow * 8;
#pragma unroll
        for (int i = 0; i < 16; i++) {
            const int r = w * 64 + i * 4 + lq;
            const uint4 val = *(const uint4*)(smem + r * 128 + (c8 ^ ((r & 7) << 3)));
            const int grow = bm * 256 + r;
            if (MODE == 1) {
                int bb = grow / FRAMES;
                int tr = grow - bb * FRAMES;
                int td = tr + SHIFT_SZ; if (td >= FRAMES) td -= FRAMES;
                const size_t dr = (size_t)(bb * FRAMES + td) * DIMC + bn * 128 + c8;
                const float4 rA = *(const float4*)(Rf + dr);
                const float4 rB = *(const float4*)(Rf + dr + 4);
                const u16* vp = (const u16*)&val;
                u16 o[8];
                o[0] = f2bf(bf2f(vp[0]) + rA.x); o[1] = f2bf(bf2f(vp[1]) + rA.y);
                o[2] = f2bf(bf2f(vp[2]) + rA.z); o[3] = f2bf(bf2f(vp[3]) + rA.w);
                o[4] = f2bf(bf2f(vp[4]) + rB.x); o[5] = f2bf(bf2f(vp[5]) + rB.y);
                o[6] = f2bf(bf2f(vp[6]) + rB.z); o[7] = f2bf(bf2f(vp[7]) + rB.w);
                uint4 ov;
                ov.x = (unsigned)o[0] | ((unsigned)o[1] << 16);
                ov.y = (unsigned)o[2] | ((unsigned)o[3] << 16);
                ov.z = (unsigned)o[4] | ((unsigned)o[5] << 16);
                ov.w = (unsigned)o[6] | ((unsigned)o[7] << 16);
                *(uint4*)(Cb + dr) = ov;
            } else {
                *(uint4*)(Cb + (size_t)grow * Nn + bn * 128 + c8) = val;
            }
        }
    } else {
        // ---- MODE 3: fp32 bounce epilogue (two 128-row passes, 64 KiB LDS) ----
        float* smf = (float*)smem;
#pragma unroll
        for (int half = 0; half < 2; half++) {
            __syncthreads();
            if (wr == half) {
#pragma unroll
                for (int m = 0; m < 8; m++) {
                    const int rl = m * 16 + lrow;                 // 0..127
#pragma unroll
                    for (int n = 0; n < 4; n++) {
                        const int col = wc * 64 + n * 16 + lq * 4;
                        const float4 b4 = *(const float4*)(bias + bn * 128 + col);
                        const int g = (col >> 2) ^ (rl & 7);      // granule swizzle
                        float4 o;
                        o.x = acc[m][n][0] + b4.x; o.y = acc[m][n][1] + b4.y;
                        o.z = acc[m][n][2] + b4.z; o.w = acc[m][n][3] + b4.w;
                        *(float4*)(smf + rl * 128 + (g << 2)) = o;
                    }
                }
            }
            __syncthreads();
            const int gq = tid & 31;
#pragma unroll
            for (int i = 0; i < 16; i++) {
                const int rl = i * 8 + (tid >> 5);
                const int gp = gq ^ (rl & 7);
                const float4 v = *(const float4*)(smf + rl * 128 + (gp << 2));
                const int grow = bm * 256 + half * 128 + rl;
                const size_t dr = (size_t)grow * Nn + bn * 128 + gq * 4;
                const ushort4 rb = *(const ushort4*)(Rb + dr);
                float4 o;
                o.x = v.x + bf2f(rb.x); o.y = v.y + bf2f(rb.y);
                o.z = v.z + bf2f(rb.z); o.w = v.w + bf2f(rb.w);
                *(float4*)(Cf + dr) = o;
            }
        }
    }
#undef COMPUTE
#undef STAGE
}

// ---------------- Windowed attention: one block per window (chunked) ----------------
__global__ __launch_bounds__(256) void attn_kernel(const u16* __restrict__ qkv_c,
                                                   const float* __restrict__ relb,
                                                   u16* __restrict__ out,
                                                   int win0) {
    __shared__ __align__(16) u16 kv[WINS * 3 * DIMC];  // 30720 B
    __shared__ float S[HEADS][WINS][WINS];
    const int tid = threadIdx.x;
    const int win = win0 + blockIdx.x;
    const u16* src = qkv_c + (size_t)blockIdx.x * (WINS * 3 * DIMC);
    for (int idx = tid * 8; idx < WINS * 3 * DIMC; idx += 2048)
        *(uint4*)(kv + idx) = *(const uint4*)(src + idx);
    __syncthreads();

    const bool lastw = (win % NWIN) == (NWIN - 1);
    for (int e = tid; e < HEADS * WINS * WINS; e += 256) {
        const int hh = e / (WINS * WINS);
        const int rem = e - hh * WINS * WINS;
        const int i = rem / WINS, j = rem - (rem / WINS) * WINS;
        const u16* qp = kv + i * (3 * DIMC) + hh * HD;
        const u16* kp = kv + j * (3 * DIMC) + DIMC + hh * HD;
        float s = 0.f;
#pragma unroll
        for (int c = 0; c < 64; c++) s += bf2f(qp[c]) * bf2f(kp[c]);
        s *= 0.125f;
        s += relb[(i - j + WINS - 1) * HEADS + hh];
        if (lastw && ((i < SHIFT_SZ) != (j < SHIFT_SZ))) s -= 100.f;
        S[hh][i][j] = s;
    }
    __syncthreads();

    if (tid < HEADS * WINS) {
        const int hh = tid / WINS, i = tid - (tid / WINS) * WINS;
        float m = -1e30f;
#pragma unroll
        for (int j = 0; j < WINS; j++) m = fmaxf(m, S[hh][i][j]);
        float e[WINS], sum = 0.f;
#pragma unroll
        for (int j = 0; j < WINS; j++) { e[j] = __expf(S[hh][i][j] - m); sum += e[j]; }
        const float inv = 1.f / sum;
#pragma unroll
        for (int j = 0; j < WINS; j++) S[hh][i][j] = e[j] * inv;
    }
    __syncthreads();

    {
        const int hh = tid >> 5, dl = tid & 31;
#pragma unroll
        for (int half = 0; half < 2; half++) {
            const int d = dl + half * 32;
            float vv[WINS];
#pragma unroll
            for (int j = 0; j < WINS; j++) vv[j] = bf2f(kv[j * (3 * DIMC) + 2 * DIMC + hh * HD + d]);
#pragma unroll
            for (int i = 0; i < WINS; i++) {
                float o = 0.f;
#pragma unroll
                for (int j = 0; j < WINS; j++) o += S[hh][i][j] * vv[j];
                out[(size_t)(win * WINS + i) * DIMC + hh * HD + d] = f2bf(o);
            }
        }
    }
}

extern "C" void kernel_launch(void* const* d_in, const int* in_sizes, int n_in,
                              void* d_out, int out_size, void* d_ws, size_t ws_size,
                              hipStream_t stream) {
    const float* x     = (const float*)d_in[0];
    const float* n1w   = (const float*)d_in[1];
    const float* n1b   = (const float*)d_in[2];
    const float* qkvw  = (const float*)d_in[3];
    const float* qkvb  = (const float*)d_in[4];
    const float* relb  = (const float*)d_in[5];
    const float* projw = (const float*)d_in[6];
    const float* projb = (const float*)d_in[7];
    const float* n2w   = (const float*)d_in[8];
    const float* n2b   = (const float*)d_in[9];
    const float* fc1w  = (const float*)d_in[10];
    const float* fc1b  = (const float*)d_in[11];
    const float* fc2w  = (const float*)d_in[12];
    const float* fc2b  = (const float*)d_in[13];

    float* outp = (float*)d_out;
    char* ws = (char*)d_ws;
    u16* wb_qkv  = (u16*)(ws);
    u16* wb_proj = (u16*)(ws + 1572864);
    u16* wb_fc1  = (u16*)(ws + 2097152);
    u16* wb_fc2  = (u16*)(ws + 4194304);
    u16* r0  = (u16*)(ws + 6291456);    // 65.536 MB: h -> attn_out -> h2 (bf16)
    u16* x2b = (u16*)(ws + 71827456);   // 65.536 MB: x2 in bf16
    u16* big = (u16*)(ws + 137363456);  // chunked qkv / fc1-activation (bf16)

    // 0) all weights fp32 -> bf16 in one dispatch
    cvt4_kernel<<<3072, 256, 0, stream>>>(qkvw, projw, fc1w, fc2w,
                                          wb_qkv, wb_proj, wb_fc1, wb_fc2);

    const size_t avail = ws_size > (size_t)137363456 ? ws_size - (size_t)137363456 : 0;
    const int nc1 = (avail >= (size_t)98304000) ? 2
                  : (avail >= (size_t)39321600) ? 5 : (avail >= (size_t)19660800) ? 10 : 50;
    const int nc2 = (avail >= (size_t)131072000) ? 2
                  : (avail >= (size_t)52428800) ? 5 : (avail >= (size_t)26214400) ? 10 : 25;

    // 1) h = LN1(x), rolled by -SHIFT
    ln_kernel<SHIFT_SZ><<<TOKENS / 4, 256, 0, stream>>>(x, n1w, n1b, r0);

    // 2+3) qkv GEMM + windowed attention, chunked
    const int rows1 = TOKENS / nc1;
    for (int c = 0; c < nc1; ++c) {
        const int row0 = c * rows1;
        gemm_bt<0><<<(rows1 / 256) * 12, 256, 0, stream>>>(
            r0 + (size_t)row0 * DIMC, wb_qkv, qkvb, big, nullptr, nullptr, nullptr, 1536, DIMC, 12);
        attn_kernel<<<rows1 / WINS, 256, 0, stream>>>(big, relb, r0, row0 / WINS);
    }

    // 4) x2b = bf16( x + roll(attn_out @ proj_w^T + proj_b, +SHIFT) )
    gemm_bt<1><<<(TOKENS / 256) * 4, 256, 0, stream>>>(
        r0, wb_proj, projb, x2b, nullptr, x, nullptr, DIMC, DIMC, 4);

    // 5) h2 = LN2(x2b) -> r0
    ln_kernel_bf<<<TOKENS / 4, 256, 0, stream>>>(x2b, n2w, n2b, r0);

    // 6+7) MLP chunked: g = gelu(h2 @ fc1^T); out = x2b + g @ fc2^T (fp32, bounced)
    const int rows2 = TOKENS / nc2;
    for (int c = 0; c < nc2; ++c) {
        const int row0 = c * rows2;
        gemm_bt<2><<<(rows2 / 256) * 16, 256, 0, stream>>>(
            r0 + (size_t)row0 * DIMC, wb_fc1, fc1b, big, nullptr, nullptr, nullptr, HIDDEN, DIMC, 16);
        gemm_bt<3><<<(rows2 / 256) * 4, 256, 0, stream>>>(
            big, wb_fc2, fc2b, nullptr, outp + (size_t)row0 * DIMC, nullptr,
            x2b + (size_t)row0 * DIMC, DIMC, HIDDEN, 4);
    }
}

// Round 20
// 713.060 us; speedup vs baseline: 1.1486x; 1.0365x over previous
//
#include <hip/hip_runtime.h>

#define DIMC 512
#define HEADS 8
#define HD 64
#define WINS 10
#define SHIFT_SZ 5
#define FRAMES 1000
#define NWIN 100
#define BATCH 64
#define TOKENS 64000
#define HIDDEN 2048

typedef unsigned short u16;
typedef __attribute__((ext_vector_type(8))) short bf16x8;
typedef __attribute__((ext_vector_type(4))) float f32x4;

__device__ __forceinline__ float bf2f(u16 u) { return __uint_as_float(((unsigned)u) << 16); }
__device__ __forceinline__ u16 f2bf(float f) {
    unsigned u = __float_as_uint(f);
    u += 0x7fffu + ((u >> 16) & 1u);
    return (u16)(u >> 16);
}
// gelu(v) ~= v * sigmoid(1.702 v) = v * rcp(1 + 2^(-1.702*log2e*v));  5 VALU ops
__device__ __forceinline__ float fast_gelu(float v) {
    return v * __builtin_amdgcn_rcpf(1.f + __builtin_amdgcn_exp2f(-2.4554677f * v));
}

// ---------------- fused fp32 -> bf16 conversion of all 4 weight matrices ----------------
__global__ __launch_bounds__(256) void cvt4_kernel(const float* __restrict__ s0,
                                                   const float* __restrict__ s1,
                                                   const float* __restrict__ s2,
                                                   const float* __restrict__ s3,
                                                   u16* __restrict__ d0, u16* __restrict__ d1,
                                                   u16* __restrict__ d2, u16* __restrict__ d3) {
    const int i = (blockIdx.x * 256 + threadIdx.x) * 4;
    const float* s; u16* d; int off;
    if (i < 786432)       { s = s0; d = d0; off = i; }
    else if (i < 1048576) { s = s1; d = d1; off = i - 786432; }
    else if (i < 2097152) { s = s2; d = d2; off = i - 1048576; }
    else                  { s = s3; d = d3; off = i - 2097152; }
    const float4 v = *(const float4*)(s + off);
    *(ushort4*)(d + off) = make_ushort4(f2bf(v.x), f2bf(v.y), f2bf(v.z), f2bf(v.w));
}

// ---------------- LayerNorm fp32-in: bf16 out rolled by -SH ----------------
template <int SH>
__global__ __launch_bounds__(256) void ln_kernel(const float* __restrict__ x,
                                                 const float* __restrict__ w,
                                                 const float* __restrict__ b,
                                                 u16* __restrict__ out) {
    const int wave = threadIdx.x >> 6, lane = threadIdx.x & 63;
    const int row = blockIdx.x * 4 + wave;
    const float4* rp = (const float4*)(x + (size_t)row * DIMC);
    const float4 v0 = rp[lane];
    const float4 v1 = rp[64 + lane];
    float f[8] = {v0.x, v0.y, v0.z, v0.w, v1.x, v1.y, v1.z, v1.w};
    float sum = 0.f, sq = 0.f;
#pragma unroll
    for (int i = 0; i < 8; i++) { sum += f[i]; sq += f[i] * f[i]; }
#pragma unroll
    for (int off = 32; off >= 1; off >>= 1) {
        sum += __shfl_xor(sum, off);
        sq += __shfl_xor(sq, off);
    }
    const float mean = sum * (1.f / DIMC);
    const float var = sq * (1.f / DIMC) - mean * mean;
    const float rstd = rsqrtf(var + 1e-5f);

    const float4 w0 = ((const float4*)w)[lane], w1 = ((const float4*)w)[64 + lane];
    const float4 b0 = ((const float4*)b)[lane], b1 = ((const float4*)b)[64 + lane];
    const float wf[8] = {w0.x, w0.y, w0.z, w0.w, w1.x, w1.y, w1.z, w1.w};
    const float bf[8] = {b0.x, b0.y, b0.z, b0.w, b1.x, b1.y, b1.z, b1.w};
    u16 o[8];
#pragma unroll
    for (int i = 0; i < 8; i++) o[i] = f2bf((f[i] - mean) * rstd * wf[i] + bf[i]);

    int dst = row;
    if (SH) {
        int bb = row / FRAMES;
        int t = row - bb * FRAMES;
        int td = t - SH; if (td < 0) td += FRAMES;
        dst = bb * FRAMES + td;
    }
    u16* op = out + (size_t)dst * DIMC;
    *(ushort4*)(op + 4 * lane) = make_ushort4(o[0], o[1], o[2], o[3]);
    *(ushort4*)(op + 256 + 4 * lane) = make_ushort4(o[4], o[5], o[6], o[7]);
}

// ---------------- LayerNorm bf16-in (for LN2 over x2b) ----------------
__global__ __launch_bounds__(256) void ln_kernel_bf(const u16* __restrict__ x,
                                                    const float* __restrict__ w,
                                                    const float* __restrict__ b,
                                                    u16* __restrict__ out) {
    const int wave = threadIdx.x >> 6, lane = threadIdx.x & 63;
    const int row = blockIdx.x * 4 + wave;
    const uint4 v = ((const uint4*)(x + (size_t)row * DIMC))[lane];
    const unsigned uv[4] = {v.x, v.y, v.z, v.w};
    float f[8];
    float sum = 0.f, sq = 0.f;
#pragma unroll
    for (int i = 0; i < 4; i++) {
        float a = __uint_as_float(uv[i] << 16);
        float c = __uint_as_float(uv[i] & 0xffff0000u);
        f[2 * i] = a; f[2 * i + 1] = c;
        sum += a + c; sq += a * a + c * c;
    }
#pragma unroll
    for (int off = 32; off >= 1; off >>= 1) {
        sum += __shfl_xor(sum, off);
        sq += __shfl_xor(sq, off);
    }
    const float mean = sum * (1.f / DIMC);
    const float var = sq * (1.f / DIMC) - mean * mean;
    const float rstd = rsqrtf(var + 1e-5f);

    const float4 w0 = ((const float4*)w)[2 * lane], w1 = ((const float4*)w)[2 * lane + 1];
    const float4 b0 = ((const float4*)b)[2 * lane], b1 = ((const float4*)b)[2 * lane + 1];
    const float wf[8] = {w0.x, w0.y, w0.z, w0.w, w1.x, w1.y, w1.z, w1.w};
    const float bf[8] = {b0.x, b0.y, b0.z, b0.w, b1.x, b1.y, b1.z, b1.w};
    u16 o[8];
#pragma unroll
    for (int i = 0; i < 8; i++) o[i] = f2bf((f[i] - mean) * rstd * wf[i] + bf[i]);
    uint4 ov;
    ov.x = (unsigned)o[0] | ((unsigned)o[1] << 16);
    ov.y = (unsigned)o[2] | ((unsigned)o[3] << 16);
    ov.z = (unsigned)o[4] | ((unsigned)o[5] << 16);
    ov.w = (unsigned)o[6] | ((unsigned)o[7] << 16);
    ((uint4*)(out + (size_t)row * DIMC))[lane] = ov;
}

// ---------------- GEMM: C = A[M,K](bf16) * W[Nn,K](bf16)^T + bias ----------------
// R13-verified K-loop: 256x128 tile, 4 waves, acc[8][4]; BK=32, 3-buffer rotating
// LDS (72 KiB, 2 blocks/CU), counted s_waitcnt vmcnt(6) + raw s_barrier (T4),
// T1 XCD remap, T2 granule-XOR. MODE 2: 5-op fast_gelu. MODE 3: fp32 LDS bounce.
#define GLD16(gp, lp)                                                                     \
    __builtin_amdgcn_global_load_lds((const __attribute__((address_space(1))) void*)(gp), \
                                     (__attribute__((address_space(3))) void*)(lp), 16, 0, 0)

template <int MODE>
__global__ __launch_bounds__(256, 2) void gemm_bt(const u16* __restrict__ A,
                                                  const u16* __restrict__ W,
                                                  const float* __restrict__ bias,
                                                  u16* __restrict__ Cb,
                                                  float* __restrict__ Cf,
                                                  const float* __restrict__ Rf,
                                                  const u16* __restrict__ Rb,
                                                  int Nn, int K, int nbn) {
    __shared__ __align__(16) u16 smem[36864];
    const int tid = threadIdx.x;
    const int w = tid >> 6, l = tid & 63;

    const int nwg = gridDim.x;
    const int q8 = nwg >> 3, r8 = nwg & 7;
    const int xcd = blockIdx.x & 7, bidx = blockIdx.x >> 3;
    const int swz = (xcd < r8 ? xcd * (q8 + 1) : r8 * (q8 + 1) + (xcd - r8) * q8) + bidx;
    const int bm = swz / nbn, bn = swz - bm * nbn;

    const int wr = w >> 1, wc = w & 1;
    const int lrow = l & 15, lq = l >> 4;

    f32x4 acc[8][4];
#pragma unroll
    for (int m = 0; m < 8; m++)
#pragma unroll
        for (int n = 0; n < 4; n++) acc[m][n] = (f32x4)0.0f;

    const int gsrc8 = (((tid & 3) ^ ((tid >> 3) & 3)) << 3);
    const u16* Ag = A + (size_t)(bm * 256 + (tid >> 2)) * K + gsrc8;
    const u16* Bg = W + (size_t)(bn * 128 + (tid >> 2)) * K + gsrc8;
    const size_t rowoff = (size_t)64 * K;
    const int lb = w * 512;

#define STAGE(buf, kt) do {                                       \
        u16* sb_ = smem + (buf) * 12288;                          \
        GLD16(Ag + (kt), sb_ + lb);                               \
        GLD16(Ag + rowoff + (kt), sb_ + 2048 + lb);               \
        GLD16(Ag + 2 * rowoff + (kt), sb_ + 4096 + lb);           \
        GLD16(Ag + 3 * rowoff + (kt), sb_ + 6144 + lb);           \
        GLD16(Bg + (kt), sb_ + 8192 + lb);                        \
        GLD16(Bg + rowoff + (kt), sb_ + 10240 + lb);              \
    } while (0)

    const int gran = ((lq ^ ((lrow >> 1) & 3)) << 3);
    const int arow = (wr * 128 + lrow) * 32 + gran;
    const int brow = 8192 + (wc * 64 + lrow) * 32 + gran;

#define COMPUTE(buf) do {                                                          \
        const u16* sb = smem + (buf) * 12288;                                      \
        bf16x8 bv[4];                                                              \
        _Pragma("unroll")                                                          \
        for (int n = 0; n < 4; n++) bv[n] = *(const bf16x8*)(sb + brow + n * 512); \
        _Pragma("unroll")                                                          \
        for (int m = 0; m < 8; m++) {                                              \
            const bf16x8 af = *(const bf16x8*)(sb + arow + m * 512);               \
            _Pragma("unroll")                                                      \
            for (int n = 0; n < 4; n++)   /* SWAPPED -> C^T fragments */           \
                acc[m][n] = __builtin_amdgcn_mfma_f32_16x16x32_bf16(bv[n], af, acc[m][n], 0, 0, 0); \
        }                                                                          \
    } while (0)

    const int nt = K >> 5;
    STAGE(0, 0);
    STAGE(1, 32);
    int cb = 0;
    for (int t = 0; t < nt - 1; ++t) {
        asm volatile("s_waitcnt vmcnt(6)" ::: "memory");
        __builtin_amdgcn_s_barrier();
        __builtin_amdgcn_sched_barrier(0);
        COMPUTE(cb);
        if (t + 2 < nt) {
            const int sbuf = cb == 0 ? 2 : cb - 1;   // (t+2) % 3
            STAGE(sbuf, (t + 2) * 32);
        }
        cb = cb == 2 ? 0 : cb + 1;
    }
    asm volatile("s_waitcnt vmcnt(0)" ::: "memory");
    __builtin_amdgcn_s_barrier();
    __builtin_amdgcn_sched_barrier(0);
    COMPUTE(cb);

    if (MODE == 0 || MODE == 1 || MODE == 2) {
        // ---- bf16 bounce epilogue: acc -> swizzled LDS -> coalesced stores ----
        __syncthreads();
#pragma unroll
        for (int m = 0; m < 8; m++) {
            const int row = wr * 128 + m * 16 + lrow;
            const int sw = (row & 7) << 3;
#pragma unroll
            for (int n = 0; n < 4; n++) {
                const int col = wc * 64 + n * 16 + lq * 4;
                const float4 b4 = *(const float4*)(bias + bn * 128 + col);
                float v0 = acc[m][n][0] + b4.x, v1 = acc[m][n][1] + b4.y;
                float v2 = acc[m][n][2] + b4.z, v3 = acc[m][n][3] + b4.w;
                if (MODE == 2) {
                    v0 = fast_gelu(v0); v1 = fast_gelu(v1);
                    v2 = fast_gelu(v2); v3 = fast_gelu(v3);
                }
                *(ushort4*)(smem + row * 128 + ((col ^ sw))) =
                    make_ushort4(f2bf(v0), f2bf(v1), f2bf(v2), f2bf(v3));
            }
        }
        __syncthreads();
        const int c8 = lrow * 8;
#pragma unroll
        for (int i = 0; i < 16; i++) {
            const int r = w * 64 + i * 4 + lq;
            const uint4 val = *(const uint4*)(smem + r * 128 + (c8 ^ ((r & 7) << 3)));
            const int grow = bm * 256 + r;
            if (MODE == 1) {
                int bb = grow / FRAMES;
                int tr = grow - bb * FRAMES;
                int td = tr + SHIFT_SZ; if (td >= FRAMES) td -= FRAMES;
                const size_t dr = (size_t)(bb * FRAMES + td) * DIMC + bn * 128 + c8;
                const float4 rA = *(const float4*)(Rf + dr);
                const float4 rB = *(const float4*)(Rf + dr + 4);
                const u16* vp = (const u16*)&val;
                u16 o[8];
                o[0] = f2bf(bf2f(vp[0]) + rA.x); o[1] = f2bf(bf2f(vp[1]) + rA.y);
                o[2] = f2bf(bf2f(vp[2]) + rA.z); o[3] = f2bf(bf2f(vp[3]) + rA.w);
                o[4] = f2bf(bf2f(vp[4]) + rB.x); o[5] = f2bf(bf2f(vp[5]) + rB.y);
                o[6] = f2bf(bf2f(vp[6]) + rB.z); o[7] = f2bf(bf2f(vp[7]) + rB.w);
                uint4 ov;
                ov.x = (unsigned)o[0] | ((unsigned)o[1] << 16);
                ov.y = (unsigned)o[2] | ((unsigned)o[3] << 16);
                ov.z = (unsigned)o[4] | ((unsigned)o[5] << 16);
                ov.w = (unsigned)o[6] | ((unsigned)o[7] << 16);
                *(uint4*)(Cb + dr) = ov;
            } else {
                *(uint4*)(Cb + (size_t)grow * Nn + bn * 128 + c8) = val;
            }
        }
    } else {
        // ---- MODE 3: fp32 bounce epilogue (two 128-row passes, 64 KiB LDS) ----
        float* smf = (float*)smem;
#pragma unroll
        for (int half = 0; half < 2; half++) {
            __syncthreads();
            if (wr == half) {
#pragma unroll
                for (int m = 0; m < 8; m++) {
                    const int rl = m * 16 + lrow;                 // 0..127
#pragma unroll
                    for (int n = 0; n < 4; n++) {
                        const int col = wc * 64 + n * 16 + lq * 4;
                        const float4 b4 = *(const float4*)(bias + bn * 128 + col);
                        const int g = (col >> 2) ^ (rl & 7);      // granule swizzle
                        float4 o;
                        o.x = acc[m][n][0] + b4.x; o.y = acc[m][n][1] + b4.y;
                        o.z = acc[m][n][2] + b4.z; o.w = acc[m][n][3] + b4.w;
                        *(float4*)(smf + rl * 128 + (g << 2)) = o;
                    }
                }
            }
            __syncthreads();
            const int gq = tid & 31;
#pragma unroll
            for (int i = 0; i < 16; i++) {
                const int rl = i * 8 + (tid >> 5);
                const int gp = gq ^ (rl & 7);
                const float4 v = *(const float4*)(smf + rl * 128 + (gp << 2));
                const int grow = bm * 256 + half * 128 + rl;
                const size_t dr = (size_t)grow * Nn + bn * 128 + gq * 4;
                const ushort4 rb = *(const ushort4*)(Rb + dr);
                float4 o;
                o.x = v.x + bf2f(rb.x); o.y = v.y + bf2f(rb.y);
                o.z = v.z + bf2f(rb.z); o.w = v.w + bf2f(rb.w);
                *(float4*)(Cf + dr) = o;
            }
        }
    }
#undef COMPUTE
#undef STAGE
}

// ---------------- Windowed attention: one block per window (chunked) ----------------
__global__ __launch_bounds__(256) void attn_kernel(const u16* __restrict__ qkv_c,
                                                   const float* __restrict__ relb,
                                                   u16* __restrict__ out,
                                                   int win0) {
    __shared__ __align__(16) u16 kv[WINS * 3 * DIMC];  // 30720 B
    __shared__ float S[HEADS][WINS][WINS];
    const int tid = threadIdx.x;
    const int win = win0 + blockIdx.x;
    const u16* src = qkv_c + (size_t)blockIdx.x * (WINS * 3 * DIMC);
    for (int idx = tid * 8; idx < WINS * 3 * DIMC; idx += 2048)
        *(uint4*)(kv + idx) = *(const uint4*)(src + idx);
    __syncthreads();

    const bool lastw = (win % NWIN) == (NWIN - 1);
    for (int e = tid; e < HEADS * WINS * WINS; e += 256) {
        const int hh = e / (WINS * WINS);
        const int rem = e - hh * WINS * WINS;
        const int i = rem / WINS, j = rem - (rem / WINS) * WINS;
        const u16* qp = kv + i * (3 * DIMC) + hh * HD;
        const u16* kp = kv + j * (3 * DIMC) + DIMC + hh * HD;
        float s = 0.f;
#pragma unroll
        for (int c = 0; c < 64; c++) s += bf2f(qp[c]) * bf2f(kp[c]);
        s *= 0.125f;
        s += relb[(i - j + WINS - 1) * HEADS + hh];
        if (lastw && ((i < SHIFT_SZ) != (j < SHIFT_SZ))) s -= 100.f;
        S[hh][i][j] = s;
    }
    __syncthreads();

    if (tid < HEADS * WINS) {
        const int hh = tid / WINS, i = tid - (tid / WINS) * WINS;
        float m = -1e30f;
#pragma unroll
        for (int j = 0; j < WINS; j++) m = fmaxf(m, S[hh][i][j]);
        float e[WINS], sum = 0.f;
#pragma unroll
        for (int j = 0; j < WINS; j++) { e[j] = __expf(S[hh][i][j] - m); sum += e[j]; }
        const float inv = __builtin_amdgcn_rcpf(sum);
#pragma unroll
        for (int j = 0; j < WINS; j++) S[hh][i][j] = e[j] * inv;
    }
    __syncthreads();

    {
        const int hh = tid >> 5, dl = tid & 31;
#pragma unroll
        for (int half = 0; half < 2; half++) {
            const int d = dl + half * 32;
            float vv[WINS];
#pragma unroll
            for (int j = 0; j < WINS; j++) vv[j] = bf2f(kv[j * (3 * DIMC) + 2 * DIMC + hh * HD + d]);
#pragma unroll
            for (int i = 0; i < WINS; i++) {
                float o = 0.f;
#pragma unroll
                for (int j = 0; j < WINS; j++) o += S[hh][i][j] * vv[j];
                out[(size_t)(win * WINS + i) * DIMC + hh * HD + d] = f2bf(o);
            }
        }
    }
}

extern "C" void kernel_launch(void* const* d_in, const int* in_sizes, int n_in,
                              void* d_out, int out_size, void* d_ws, size_t ws_size,
                              hipStream_t stream) {
    const float* x     = (const float*)d_in[0];
    const float* n1w   = (const float*)d_in[1];
    const float* n1b   = (const float*)d_in[2];
    const float* qkvw  = (const float*)d_in[3];
    const float* qkvb  = (const float*)d_in[4];
    const float* relb  = (const float*)d_in[5];
    const float* projw = (const float*)d_in[6];
    const float* projb = (const float*)d_in[7];
    const float* n2w   = (const float*)d_in[8];
    const float* n2b   = (const float*)d_in[9];
    const float* fc1w  = (const float*)d_in[10];
    const float* fc1b  = (const float*)d_in[11];
    const float* fc2w  = (const float*)d_in[12];
    const float* fc2b  = (const float*)d_in[13];

    float* outp = (float*)d_out;
    char* ws = (char*)d_ws;
    u16* wb_qkv  = (u16*)(ws);
    u16* wb_proj = (u16*)(ws + 1572864);
    u16* wb_fc1  = (u16*)(ws + 2097152);
    u16* wb_fc2  = (u16*)(ws + 4194304);
    u16* r0  = (u16*)(ws + 6291456);    // 65.536 MB: h -> attn_out -> h2 (bf16)
    u16* x2b = (u16*)(ws + 71827456);   // 65.536 MB: x2 in bf16
    u16* big = (u16*)(ws + 137363456);  // chunked qkv / fc1-activation (bf16)

    // 0) all weights fp32 -> bf16 in one dispatch
    cvt4_kernel<<<3072, 256, 0, stream>>>(qkvw, projw, fc1w, fc2w,
                                          wb_qkv, wb_proj, wb_fc1, wb_fc2);

    const size_t avail = ws_size > (size_t)137363456 ? ws_size - (size_t)137363456 : 0;
    const int nc1 = (avail >= (size_t)98304000) ? 2
                  : (avail >= (size_t)39321600) ? 5 : (avail >= (size_t)19660800) ? 10 : 50;
    const int nc2 = (avail >= (size_t)131072000) ? 2
                  : (avail >= (size_t)52428800) ? 5 : (avail >= (size_t)26214400) ? 10 : 25;

    // 1) h = LN1(x), rolled by -SHIFT
    ln_kernel<SHIFT_SZ><<<TOKENS / 4, 256, 0, stream>>>(x, n1w, n1b, r0);

    // 2+3) qkv GEMM + windowed attention, chunked
    const int rows1 = TOKENS / nc1;
    for (int c = 0; c < nc1; ++c) {
        const int row0 = c * rows1;
        gemm_bt<0><<<(rows1 / 256) * 12, 256, 0, stream>>>(
            r0 + (size_t)row0 * DIMC, wb_qkv, qkvb, big, nullptr, nullptr, nullptr, 1536, DIMC, 12);
        attn_kernel<<<rows1 / WINS, 256, 0, stream>>>(big, relb, r0, row0 / WINS);
    }

    // 4) x2b = bf16( x + roll(attn_out @ proj_w^T + proj_b, +SHIFT) )
    gemm_bt<1><<<(TOKENS / 256) * 4, 256, 0, stream>>>(
        r0, wb_proj, projb, x2b, nullptr, x, nullptr, DIMC, DIMC, 4);

    // 5) h2 = LN2(x2b) -> r0
    ln_kernel_bf<<<TOKENS / 4, 256, 0, stream>>>(x2b, n2w, n2b, r0);

    // 6+7) MLP chunked: g = gelu(h2 @ fc1^T); out = x2b + g @ fc2^T (fp32, bounced)
    const int rows2 = TOKENS / nc2;
    for (int c = 0; c < nc2; ++c) {
        const int row0 = c * rows2;
        gemm_bt<2><<<(rows2 / 256) * 16, 256, 0, stream>>>(
            r0 + (size_t)row0 * DIMC, wb_fc1, fc1b, big, nullptr, nullptr, nullptr, HIDDEN, DIMC, 16);
        gemm_bt<3><<<(rows2 / 256) * 4, 256, 0, stream>>>(
            big, wb_fc2, fc2b, nullptr, outp + (size_t)row0 * DIMC, nullptr,
            x2b + (size_t)row0 * DIMC, DIMC, HIDDEN, 4);
    }
}